// Round 3
// baseline (11.716 us; speedup 1.0000x reference)
//
#include <hip/hip_runtime.h>
#include <hip/hip_bf16.h>
#include <math.h>

// feature [1,2,96,160] f32, boxes [128,4] f32, fc_w [4,98] f32, fc_b [4] f32.
// out[n] = relu(adaptive_maxpool7x7(crop_n) . fc_w^T + fc_b) + boxes[n]
//
// Cell i over [lo,hi), h=hi-lo: [lo+floor(i*h/7), lo+ceil((i+1)*h/7)).
// h,w in [5,48] => cells span <=8x8 and the 8x8 window at (rs,cs) is
// always in-bounds (x1<=W-50, y1<=H-50).
//
// R3 changes (pure latency-chain surgery; kernel is launch-floor bound):
//  - fc_w loads hoisted to kernel top (box-independent) -> overlap feature
//    loads instead of serializing after the barrier.
//  - depth-6 tree max instead of 64-deep serial fmax chain.
//  - FC as distributed products + __shfl_xor wave reduction (pooled value
//    stays in the owning thread's register; no pooled[] LDS round-trip,
//    no 98-deep serial FMA chain).

#define C_ 2
#define H_ 96
#define W_ 160
#define P_ 7
#define CELLS (C_ * P_ * P_)  // 98

__global__ void __launch_bounds__(128)
roi_pool_fc_kernel(const float* __restrict__ feature, // [C,H,W]
                   const float* __restrict__ boxes,   // [N,4]
                   const float* __restrict__ fc_w,    // [4,98]
                   const float* __restrict__ fc_b,    // [4]
                   float* __restrict__ out)           // [N,4]
{
    const int n = blockIdx.x;
    const int t = threadIdx.x;

    __shared__ float partial[2][4];

    // ---- issue box-independent loads first (overlap with everything) ----
    float w0 = 0.f, w1 = 0.f, w2 = 0.f, w3 = 0.f;
    if (t < CELLS) {
        w0 = fc_w[0 * CELLS + t];
        w1 = fc_w[1 * CELLS + t];
        w2 = fc_w[2 * CELLS + t];
        w3 = fc_w[3 * CELLS + t];
    }

    // Uniform address -> scalar dwordx4 load.
    const float4 b = ((const float4*)boxes)[n];
    const int x1 = (int)b.x;   // positive -> trunc == floor
    const int y1 = (int)b.y;
    const int x2 = (int)b.z;
    const int y2 = (int)b.w;
    const int hh = y2 - y1;    // in [5,48]
    const int ww = x2 - x1;

    float m = 0.f;  // inactive threads contribute 0 to the FC sums
    if (t < CELLS) {
        const int c   = t / (P_ * P_);
        const int rem = t % (P_ * P_);
        const int py  = rem / P_;
        const int px  = rem % P_;

        const int rs = y1 + (py * hh) / P_;
        const int re = y1 + ((py + 1) * hh + (P_ - 1)) / P_;  // ceil
        const int cs = x1 + (px * ww) / P_;
        const int ce = x1 + ((px + 1) * ww + (P_ - 1)) / P_;
        const int nr = re - rs;  // 1..8
        const int nc = ce - cs;  // 1..8

        const float* __restrict__ base = feature + c * (H_ * W_) + rs * W_ + cs;

        // Batch all 64 window loads (one vmcnt drain, not 64).
        float v[64];
        #pragma unroll
        for (int i = 0; i < 64; ++i)
            v[i] = base[(i >> 3) * W_ + (i & 7)];

        #pragma unroll
        for (int i = 0; i < 64; ++i) {
            const bool ok = ((i >> 3) < nr) & ((i & 7) < nc);
            v[i] = ok ? v[i] : -INFINITY;
        }
        // Depth-6 tree max (dep latency ~24 cy vs ~256 serial).
        #pragma unroll
        for (int s = 32; s > 0; s >>= 1) {
            #pragma unroll
            for (int i = 0; i < s; ++i)
                v[i] = fmaxf(v[i], v[i + s]);
        }
        m = v[0];
    }

    // ---- FC: distributed products + butterfly wave reduction ----
    float p0 = m * w0, p1 = m * w1, p2 = m * w2, p3 = m * w3;
    #pragma unroll
    for (int s = 32; s > 0; s >>= 1) {
        p0 += __shfl_xor(p0, s);
        p1 += __shfl_xor(p1, s);
        p2 += __shfl_xor(p2, s);
        p3 += __shfl_xor(p3, s);
    }
    const int wv = t >> 6;
    if ((t & 63) == 0) {
        partial[wv][0] = p0; partial[wv][1] = p1;
        partial[wv][2] = p2; partial[wv][3] = p3;
    }
    __syncthreads();

    if (t < 4) {
        const float acc = partial[0][t] + partial[1][t] + fc_b[t];
        const float bc = (t == 0) ? b.x : (t == 1) ? b.y : (t == 2) ? b.z : b.w;
        out[n * 4 + t] = fmaxf(acc, 0.f) + bc;
    }
}

extern "C" void kernel_launch(void* const* d_in, const int* in_sizes, int n_in,
                              void* d_out, int out_size, void* d_ws, size_t ws_size,
                              hipStream_t stream) {
    const float* feature = (const float*)d_in[0];
    const float* boxes   = (const float*)d_in[1];
    const float* fc_w    = (const float*)d_in[2];
    const float* fc_b    = (const float*)d_in[3];
    float* out = (float*)d_out;

    const int N = in_sizes[1] / 4;  // 128

    roi_pool_fc_kernel<<<N, 128, 0, stream>>>(feature, boxes, fc_w, fc_b, out);
}

// Round 4
// 9.720 us; speedup vs baseline: 1.2054x; 1.2054x over previous
//
#include <hip/hip_runtime.h>
#include <hip/hip_bf16.h>
#include <math.h>

// feature [1,2,96,160] f32, boxes [128,4] f32, fc_w [4,98] f32, fc_b [4] f32.
// out[n] = relu(adaptive_maxpool7x7(crop_n) . fc_w^T + fc_b) + boxes[n]
//
// Cell i over [lo,hi), h=hi-lo: [lo+floor(i*h/7), lo+ceil((i+1)*h/7)).
// h,w in [5,48] => cells span <=8x8 and the 8x8 window at (rs,cs) is
// always in-bounds.
//
// R4 = R2 (best measured, 9.6us) + safe-only tweaks:
//  - fc_w/fc_b loads hoisted ABOVE the pooling phase (box-independent;
//    latency overlaps the feature-window loads instead of serializing
//    after the barrier).
//  - depth-6 tree max instead of the 64-deep serial fmax chain.
//  - NO shfl butterfly (R3's suspect regression): FC stays on 4 threads
//    reading pooled[] from LDS.
// Kernel critical path is ~0.3us; measured time is dominated by the
// graph-replay launch floor (~9-10us).

#define C_ 2
#define H_ 96
#define W_ 160
#define P_ 7
#define CELLS (C_ * P_ * P_)  // 98

__global__ void __launch_bounds__(128)
roi_pool_fc_kernel(const float* __restrict__ feature, // [C,H,W]
                   const float* __restrict__ boxes,   // [N,4]
                   const float* __restrict__ fc_w,    // [4,98]
                   const float* __restrict__ fc_b,    // [4]
                   float* __restrict__ out)           // [N,4]
{
    const int n = blockIdx.x;
    const int t = threadIdx.x;

    __shared__ float pooled[CELLS];

    // ---- hoisted box-independent FC loads (t<4 only uses them) ----
    float w[CELLS];
    float bias = 0.f;
    if (t < 4) {
        const float* __restrict__ wrow = fc_w + t * CELLS;
        #pragma unroll
        for (int k = 0; k < CELLS; ++k) w[k] = wrow[k];
        bias = fc_b[t];
    }

    // Uniform address -> scalar dwordx4 load.
    const float4 b = ((const float4*)boxes)[n];
    const int x1 = (int)b.x;   // positive -> trunc == floor
    const int y1 = (int)b.y;
    const int x2 = (int)b.z;
    const int y2 = (int)b.w;
    const int hh = y2 - y1;    // in [5,48]
    const int ww = x2 - x1;

    if (t < CELLS) {
        const int c   = t / (P_ * P_);
        const int rem = t % (P_ * P_);
        const int py  = rem / P_;
        const int px  = rem % P_;

        const int rs = y1 + (py * hh) / P_;
        const int re = y1 + ((py + 1) * hh + (P_ - 1)) / P_;  // ceil
        const int cs = x1 + (px * ww) / P_;
        const int ce = x1 + ((px + 1) * ww + (P_ - 1)) / P_;
        const int nr = re - rs;  // 1..8
        const int nc = ce - cs;  // 1..8

        const float* __restrict__ base = feature + c * (H_ * W_) + rs * W_ + cs;

        // Batch all 64 window loads (one vmcnt drain, not 64 round-trips).
        float v[64];
        #pragma unroll
        for (int i = 0; i < 64; ++i)
            v[i] = base[(i >> 3) * W_ + (i & 7)];

        #pragma unroll
        for (int i = 0; i < 64; ++i) {
            const bool ok = ((i >> 3) < nr) & ((i & 7) < nc);
            v[i] = ok ? v[i] : -INFINITY;
        }
        // Depth-6 tree max.
        #pragma unroll
        for (int s = 32; s > 0; s >>= 1) {
            #pragma unroll
            for (int i = 0; i < s; ++i)
                v[i] = fmaxf(v[i], v[i + s]);
        }
        pooled[t] = v[0];
    }
    __syncthreads();

    if (t < 4) {
        float p[CELLS];
        #pragma unroll
        for (int k = 0; k < CELLS; ++k) p[k] = pooled[k];
        float acc = bias;
        #pragma unroll
        for (int k = 0; k < CELLS; ++k)
            acc = fmaf(p[k], w[k], acc);
        const float bc = (t == 0) ? b.x : (t == 1) ? b.y : (t == 2) ? b.z : b.w;
        out[n * 4 + t] = fmaxf(acc, 0.f) + bc;
    }
}

extern "C" void kernel_launch(void* const* d_in, const int* in_sizes, int n_in,
                              void* d_out, int out_size, void* d_ws, size_t ws_size,
                              hipStream_t stream) {
    const float* feature = (const float*)d_in[0];
    const float* boxes   = (const float*)d_in[1];
    const float* fc_w    = (const float*)d_in[2];
    const float* fc_b    = (const float*)d_in[3];
    float* out = (float*)d_out;

    const int N = in_sizes[1] / 4;  // 128

    roi_pool_fc_kernel<<<N, 128, 0, stream>>>(feature, boxes, fc_w, fc_b, out);
}

// Round 5
// 9.544 us; speedup vs baseline: 1.2275x; 1.0184x over previous
//
#include <hip/hip_runtime.h>
#include <hip/hip_bf16.h>
#include <math.h>

// feature [1,2,96,160] f32, boxes [128,4] f32, fc_w [4,98] f32, fc_b [4] f32.
// out[n] = relu(adaptive_maxpool7x7(crop_n) . fc_w^T + fc_b) + boxes[n]
//
// Cell i over [lo,hi), h=hi-lo: [lo+floor(i*h/7), lo+ceil((i+1)*h/7)).
// h,w in [5,48] => cells span <=8x8 and the 8x8 window at (rs,cs) is
// always in-bounds.
//
// R5 = R4 VERBATIM (noise-band probe). R2=9.60, R3=11.72, R4=9.72:
// R3's +2.1us regression is unexplainable by its code delta (~0.35us),
// so this run measures run-to-run noise on an identical binary before
// declaring the launch-floor ceiling. Kernel critical path ~0.7us;
// measured time is dominated by the graph-replay dispatch floor.

#define C_ 2
#define H_ 96
#define W_ 160
#define P_ 7
#define CELLS (C_ * P_ * P_)  // 98

__global__ void __launch_bounds__(128)
roi_pool_fc_kernel(const float* __restrict__ feature, // [C,H,W]
                   const float* __restrict__ boxes,   // [N,4]
                   const float* __restrict__ fc_w,    // [4,98]
                   const float* __restrict__ fc_b,    // [4]
                   float* __restrict__ out)           // [N,4]
{
    const int n = blockIdx.x;
    const int t = threadIdx.x;

    __shared__ float pooled[CELLS];

    // ---- hoisted box-independent FC loads (t<4 only uses them) ----
    float w[CELLS];
    float bias = 0.f;
    if (t < 4) {
        const float* __restrict__ wrow = fc_w + t * CELLS;
        #pragma unroll
        for (int k = 0; k < CELLS; ++k) w[k] = wrow[k];
        bias = fc_b[t];
    }

    // Uniform address -> scalar dwordx4 load.
    const float4 b = ((const float4*)boxes)[n];
    const int x1 = (int)b.x;   // positive -> trunc == floor
    const int y1 = (int)b.y;
    const int x2 = (int)b.z;
    const int y2 = (int)b.w;
    const int hh = y2 - y1;    // in [5,48]
    const int ww = x2 - x1;

    if (t < CELLS) {
        const int c   = t / (P_ * P_);
        const int rem = t % (P_ * P_);
        const int py  = rem / P_;
        const int px  = rem % P_;

        const int rs = y1 + (py * hh) / P_;
        const int re = y1 + ((py + 1) * hh + (P_ - 1)) / P_;  // ceil
        const int cs = x1 + (px * ww) / P_;
        const int ce = x1 + ((px + 1) * ww + (P_ - 1)) / P_;
        const int nr = re - rs;  // 1..8
        const int nc = ce - cs;  // 1..8

        const float* __restrict__ base = feature + c * (H_ * W_) + rs * W_ + cs;

        // Batch all 64 window loads (one vmcnt drain, not 64 round-trips).
        float v[64];
        #pragma unroll
        for (int i = 0; i < 64; ++i)
            v[i] = base[(i >> 3) * W_ + (i & 7)];

        #pragma unroll
        for (int i = 0; i < 64; ++i) {
            const bool ok = ((i >> 3) < nr) & ((i & 7) < nc);
            v[i] = ok ? v[i] : -INFINITY;
        }
        // Depth-6 tree max.
        #pragma unroll
        for (int s = 32; s > 0; s >>= 1) {
            #pragma unroll
            for (int i = 0; i < s; ++i)
                v[i] = fmaxf(v[i], v[i + s]);
        }
        pooled[t] = v[0];
    }
    __syncthreads();

    if (t < 4) {
        float p[CELLS];
        #pragma unroll
        for (int k = 0; k < CELLS; ++k) p[k] = pooled[k];
        float acc = bias;
        #pragma unroll
        for (int k = 0; k < CELLS; ++k)
            acc = fmaf(p[k], w[k], acc);
        const float bc = (t == 0) ? b.x : (t == 1) ? b.y : (t == 2) ? b.z : b.w;
        out[n * 4 + t] = fmaxf(acc, 0.f) + bc;
    }
}

extern "C" void kernel_launch(void* const* d_in, const int* in_sizes, int n_in,
                              void* d_out, int out_size, void* d_ws, size_t ws_size,
                              hipStream_t stream) {
    const float* feature = (const float*)d_in[0];
    const float* boxes   = (const float*)d_in[1];
    const float* fc_w    = (const float*)d_in[2];
    const float* fc_b    = (const float*)d_in[3];
    float* out = (float*)d_out;

    const int N = in_sizes[1] / 4;  // 128

    roi_pool_fc_kernel<<<N, 128, 0, stream>>>(feature, boxes, fc_w, fc_b, out);
}